// Round 6
// baseline (231.199 us; speedup 1.0000x reference)
//
#include <hip/hip_runtime.h>
#include <stdint.h>
#include <math.h>

#define B_ 4
#define T_ 4096
#define C_ 1024
#define H_ 128

typedef __attribute__((ext_vector_type(8))) short s16x8;   // 8 bf16 (4 VGPRs)
typedef __attribute__((ext_vector_type(4))) float f32x4;   // MFMA accumulator

__device__ __forceinline__ unsigned short f2bf(float f) {
    union { float f; unsigned u; } v; v.f = f;
    unsigned r = v.u + 0x7fffu + ((v.u >> 16) & 1u);
    return (unsigned short)(r >> 16);
}

__device__ __forceinline__ s16x8 as_frag(uint4 u) {
    union { uint4 u; s16x8 s; } v; v.u = u; return v.s;
}

// chunks per batch for 128-query blocks, CH key-tiles per chunk (CH even).
// q-block qb (0..31) has 2qb+2 key-tiles; nc(qb) = ceil((2qb+2)/CH) =
// ceil((qb+1)/(CH/2)).  Total = F(32) with F(n) = sum_{m=1..n} ceil(m/H2).
__host__ __device__ constexpr int chunks128(int CH) {
    int H2 = CH / 2;
    int k = 32 / H2, r = 32 % H2;
    return H2 * k * (k + 1) / 2 + r * (k + 1);
}

// softmax scale folded into Q at projection time: 1/sqrt(128) * log2(e)
#define QSC (0.0883883476f * 1.4426950408f)

// ---------------------------------------------------------------------------
// Kernel 1: W [1024][128] fp32 -> Wt [3*128][1024] bf16 (transposed, converted)
// ---------------------------------------------------------------------------
__global__ __launch_bounds__(256) void k_wt(const float* __restrict__ Wk,
                                            const float* __restrict__ Wq,
                                            const float* __restrict__ Wv,
                                            unsigned short* __restrict__ Wt) {
    __shared__ float tile[64][65];
    int w = blockIdx.z;  // 0=K, 1=Q, 2=V
    const float* W = (w == 0) ? Wk : (w == 1) ? Wq : Wv;
    int c0 = blockIdx.x * 64, h0 = blockIdx.y * 64;
    int tid = threadIdx.x;
#pragma unroll
    for (int k = 0; k < 16; k++) {
        int idx = tid + k * 256;
        int r = idx >> 6, c = idx & 63;
        tile[r][c] = W[(size_t)(c0 + r) * H_ + h0 + c];
    }
    __syncthreads();
#pragma unroll
    for (int k = 0; k < 16; k++) {
        int idx = tid + k * 256;
        int hh = idx >> 6, cc = idx & 63;
        Wt[(size_t)(w * H_ + h0 + hh) * C_ + c0 + cc] = f2bf(tile[cc][hh]);
    }
}

// ---------------------------------------------------------------------------
// Kernel 2: fused QKV GEMM — ROUND-0 EXACT (best measured: 43.1us, VGPR 64).
// Five variants (2-deep x, B-prefetch, split-K x2, retile) all measured worse:
// k_qkv is not improvable by source-level scheduling/occupancy moves.
// V is written t-PERMUTED within each 32-block (consumed by k_attn PV order).
// ---------------------------------------------------------------------------
__global__ __launch_bounds__(256, 3) void k_qkv(const float* __restrict__ x,
                                                const unsigned short* __restrict__ Wt,
                                                unsigned short* __restrict__ Qb,
                                                unsigned short* __restrict__ Kb,
                                                unsigned short* __restrict__ Vt) {
    __shared__ unsigned short a_lds[2][64 * 72];  // 2 x 9216 B
    int tid = threadIdx.x;
    int wv = tid >> 6, lane = tid & 63, quad = lane >> 4, lo = lane & 15;
    int r0 = blockIdx.x * 64;
    int cb = blockIdx.y;
    int nt0 = wv * 3;

    f32x4 acc[3][4];
#pragma unroll
    for (int i = 0; i < 3; i++)
#pragma unroll
        for (int j = 0; j < 4; j++) acc[i][j] = (f32x4){0.f, 0.f, 0.f, 0.f};

    const int row_s = tid >> 2;
    const int seg_s = (tid & 3) * 16;
    size_t xbase = (size_t)(r0 + row_s) * C_ + seg_s;

    const unsigned short* wp[3];
#pragma unroll
    for (int nt = 0; nt < 3; nt++)
        wp[nt] = Wt + (size_t)(cb * 192 + (nt0 + nt) * 16 + lo) * C_ + quad * 8;

    auto pack_store = [&](unsigned short* buf, const float4 (&f)[4]) {
        uint4 u0, u1;
        u0.x = (unsigned)f2bf(f[0].x) | ((unsigned)f2bf(f[0].y) << 16);
        u0.y = (unsigned)f2bf(f[0].z) | ((unsigned)f2bf(f[0].w) << 16);
        u0.z = (unsigned)f2bf(f[1].x) | ((unsigned)f2bf(f[1].y) << 16);
        u0.w = (unsigned)f2bf(f[1].z) | ((unsigned)f2bf(f[1].w) << 16);
        u1.x = (unsigned)f2bf(f[2].x) | ((unsigned)f2bf(f[2].y) << 16);
        u1.y = (unsigned)f2bf(f[2].z) | ((unsigned)f2bf(f[2].w) << 16);
        u1.z = (unsigned)f2bf(f[3].x) | ((unsigned)f2bf(f[3].y) << 16);
        u1.w = (unsigned)f2bf(f[3].z) | ((unsigned)f2bf(f[3].w) << 16);
        *(uint4*)&buf[row_s * 72 + seg_s] = u0;
        *(uint4*)&buf[row_s * 72 + seg_s + 8] = u1;
    };
    auto load_x = [&](float4 (&f)[4], int kc) {
        const float* xp = x + xbase + kc * 64;
#pragma unroll
        for (int j = 0; j < 4; j++) f[j] = *(const float4*)(xp + j * 4);
    };

    float4 xr[4];
    load_x(xr, 0);
    pack_store(a_lds[0], xr);
    __syncthreads();

    for (int kc = 0; kc < 16; kc++) {
        const unsigned short* buf = a_lds[kc & 1];
        float4 xn[4];
        if (kc < 15) load_x(xn, kc + 1);  // HBM prefetch; lands during gemm
        s16x8 b[3][2];
#pragma unroll
        for (int nt = 0; nt < 3; nt++)
#pragma unroll
            for (int kh = 0; kh < 2; kh++)
                b[nt][kh] = *(const s16x8*)(wp[nt] + kc * 64 + kh * 32);
        s16x8 af[4][2];
#pragma unroll
        for (int mt = 0; mt < 4; mt++)
#pragma unroll
            for (int kh = 0; kh < 2; kh++)
                af[mt][kh] = *(const s16x8*)&buf[(mt * 16 + lo) * 72 + kh * 32 + quad * 8];
#pragma unroll
        for (int nt = 0; nt < 3; nt++)
#pragma unroll
            for (int kh = 0; kh < 2; kh++)
#pragma unroll
                for (int mt = 0; mt < 4; mt++)
                    acc[nt][mt] = __builtin_amdgcn_mfma_f32_16x16x32_bf16(
                        af[mt][kh], b[nt][kh], acc[nt][mt], 0, 0, 0);
        if (kc < 15) pack_store((unsigned short*)a_lds[(kc & 1) ^ 1], xn);
        __syncthreads();  // next buf ready AND current buf's reads done
    }

    // Epilogue. C-layout: row = mt*16 + quad*4 + r, col = cb*192 + (nt0+nt)*16 + lo
#pragma unroll
    for (int nt = 0; nt < 3; nt++) {
        int col = cb * 192 + (nt0 + nt) * 16 + lo;
        int w = col >> 7, h = col & 127;
#pragma unroll
        for (int mt = 0; mt < 4; mt++) {
            int mrow = r0 + mt * 16 + quad * 4;
            if (w == 2) {
                int b = mrow >> 12, t0 = mrow & 4095;
                // permuted t within 32-block (see k_attn PV fragment order)
                int tp = (t0 & ~31) + (((t0 & 15) >> 2) << 3) + (((t0 >> 4) & 1) << 2);
                uint2 pk;
                pk.x = (unsigned)f2bf(acc[nt][mt][0]) | ((unsigned)f2bf(acc[nt][mt][1]) << 16);
                pk.y = (unsigned)f2bf(acc[nt][mt][2]) | ((unsigned)f2bf(acc[nt][mt][3]) << 16);
                *(uint2*)(Vt + (size_t)(b * H_ + h) * T_ + tp) = pk;
            } else if (w == 1) {
                unsigned short* dst = Qb + (size_t)mrow * H_ + h;
#pragma unroll
                for (int r = 0; r < 4; r++)
                    dst[(size_t)r * H_] = f2bf(acc[nt][mt][r] * QSC);
            } else {
                unsigned short* dst = Kb + (size_t)mrow * H_ + h;
#pragma unroll
                for (int r = 0; r < 4; r++)
                    dst[(size_t)r * H_] = f2bf(acc[nt][mt][r]);
            }
        }
    }
}

// ---------------------------------------------------------------------------
// Kernel 3: causal flash attention, S^T formulation.
// ROUND-6: 128-QUERY BLOCKS (512 thr, 8 waves x 16 queries). Per-wave code is
// byte-identical to the proven VGPR-64 kernel; 8 waves now share ONE K/V
// staging -> tile-units 8320 -> 4224: K/V global traffic, LDS staging writes
// and barrier count per unit work all HALVE. (Five prior theories — pipeline
// depth, occupancy, balance, setprio, XCD placement — all null; the per-tile
// serial overhead x tile-count is what's left, so cut tile-count.)
// Equal-work chunking: CH key-tiles per block; grid 4*chunks128(CH), all
// co-resident (CH=6: 748 blocks = ~3/CU, 96KB LDS, 24 waves/CU).
// Mask condition is per-wave: kv0+63 > m0 (waves 0-3 waste the final odd
// tile of their qb: ~1.5% of work, exp(-inf)=0 keeps it correct).
// ---------------------------------------------------------------------------
#define LOAD_KV(kv0)                                                            \
    do {                                                                        \
        const uint4* kg = (const uint4*)(Kb + (size_t)(batch * T_ + (kv0) + srow_k) * H_); \
        pk0 = kg[sseg_k + 0]; pk1 = kg[sseg_k + 1];                             \
        const uint4* vg = (const uint4*)(Vt + (size_t)(batch * H_ + srow_v) * T_ + (kv0)); \
        pv0 = vg[sseg_v + 0]; pv1 = vg[sseg_v + 1];                             \
    } while (0)

template <int CH>
__global__ __launch_bounds__(512, 6) void k_attn(const unsigned short* __restrict__ Qb,
                                                 const unsigned short* __restrict__ Kb,
                                                 const unsigned short* __restrict__ Vt,
                                                 float* __restrict__ Opart,
                                                 float* __restrict__ Mpart,
                                                 float* __restrict__ Lpart) {
    __shared__ uint4 kbuf[64 * 16];   // 16 KB (64 keys x 128d, swizzled)
    __shared__ uint4 vbuf[128 * 8];   // 16 KB (t-permuted V^T rows)

    int tid = threadIdx.x;
    int wv = tid >> 6, lane = tid & 63, quad = lane >> 4, lo = lane & 15;

    int id = blockIdx.x;
    int batch = id & 3;
    int slot = id >> 2;                    // slot ascending <=> qb descending
    int s = slot, q = 31;
    for (;;) { int nc = (2 * q + 1 + CH) / CH; if (s < nc) break; s -= nc; --q; }
    int qb = q;
    int tbeg = s * CH;
    int tend = min(tbeg + CH, 2 * qb + 2);
    int m0 = qb * 128 + wv * 16;
    int query = m0 + lo;

    s16x8 qf[4];
    size_t qrow = (size_t)(batch * T_ + m0 + lo) * H_;
#pragma unroll
    for (int ks = 0; ks < 4; ks++)
        qf[ks] = *(const s16x8*)(Qb + qrow + ks * 32 + quad * 8);

    f32x4 acc_o[8];   // O[query=lo][d = o*16 + quad*4 + r]
#pragma unroll
    for (int o = 0; o < 8; o++) acc_o[o] = (f32x4){0.f, 0.f, 0.f, 0.f};
    float m_i = -INFINITY, l_i = 0.f;   // l_i: per-lane PARTIAL (quad slice)

    // staging map for 512 threads: K 8 thr/row x 32B, V 4 thr/row x 32B
    const int srow_k = tid >> 3, sseg_k = (tid & 7) * 2;
    const int srow_v = tid >> 2, sseg_v = (tid & 3) * 2;

    uint4 pk0, pk1, pv0, pv1;
    LOAD_KV(tbeg * 64);

    for (int t = tbeg; t < tend; ++t) {
        int kv0 = t * 64;
        kbuf[srow_k * 16 + ((sseg_k + 0) ^ (srow_k & 15))] = pk0;
        kbuf[srow_k * 16 + ((sseg_k + 1) ^ (srow_k & 15))] = pk1;
        vbuf[srow_v * 8 + ((sseg_v + 0) ^ (srow_v & 7))] = pv0;
        vbuf[srow_v * 8 + ((sseg_v + 1) ^ (srow_v & 7))] = pv1;
        __syncthreads();
        if (t + 1 < tend) LOAD_KV((t + 1) * 64);

        // S^T = K Q^T: lane holds S[query=lo][key = kv0 + nt*16 + quad*4 + r]
        f32x4 s_acc[4];
#pragma unroll
        for (int nt = 0; nt < 4; nt++) s_acc[nt] = (f32x4){0.f, 0.f, 0.f, 0.f};
        __builtin_amdgcn_s_setprio(1);
#pragma unroll
        for (int ks = 0; ks < 4; ks++) {
#pragma unroll
            for (int nt = 0; nt < 4; nt++) {
                s16x8 kf = as_frag(kbuf[(nt * 16 + lo) * 16 + ((ks * 4 + quad) ^ lo)]);
                s_acc[nt] = __builtin_amdgcn_mfma_f32_16x16x32_bf16(kf, qf[ks], s_acc[nt], 0, 0, 0);
            }
        }
        __builtin_amdgcn_s_setprio(0);

        float p[4][4];
#pragma unroll
        for (int nt = 0; nt < 4; nt++)
#pragma unroll
            for (int r = 0; r < 4; r++) p[nt][r] = s_acc[nt][r];
        if (kv0 + 63 > m0) {  // wave-uniform: tile may contain keys > queries
#pragma unroll
            for (int nt = 0; nt < 4; nt++)
#pragma unroll
                for (int r = 0; r < 4; r++)
                    if (kv0 + nt * 16 + quad * 4 + r > query) p[nt][r] = -INFINITY;
        }

        // per-lane max only; cross-lane work deferred (T13, THR=8)
        float mx = p[0][0];
#pragma unroll
        for (int nt = 0; nt < 4; nt++)
#pragma unroll
            for (int r = 0; r < 4; r++) mx = fmaxf(mx, p[nt][r]);
        if (__any(mx > m_i + 8.0f)) {
            float rm = fmaxf(mx, __shfl_xor(mx, 16));
            rm = fmaxf(rm, __shfl_xor(rm, 32));
            float mnew = fmaxf(m_i, rm);
            float alpha = exp2f(m_i - mnew);
            l_i *= alpha;
            m_i = mnew;
#pragma unroll
            for (int o = 0; o < 8; o++)
#pragma unroll
                for (int r = 0; r < 4; r++) acc_o[o][r] *= alpha;
        }
        float rs = 0.f;
#pragma unroll
        for (int nt = 0; nt < 4; nt++)
#pragma unroll
            for (int r = 0; r < 4; r++) {
                float pv = exp2f(p[nt][r] - m_i);   // bounded by 2^8
                p[nt][r] = pv;
                rs += pv;
            }
        l_i += rs;   // per-lane partial; summed across quads after loop

        // pack P straight into B-fragments (truncation; P in [0, 256])
        s16x8 pf[2];
#pragma unroll
        for (int kt = 0; kt < 2; kt++) {
            uint4 u;
            u.x = (__float_as_uint(p[2 * kt][0]) >> 16) | ((__float_as_uint(p[2 * kt][1]) >> 16) << 16);
            u.y = (__float_as_uint(p[2 * kt][2]) >> 16) | ((__float_as_uint(p[2 * kt][3]) >> 16) << 16);
            u.z = (__float_as_uint(p[2 * kt + 1][0]) >> 16) | ((__float_as_uint(p[2 * kt + 1][1]) >> 16) << 16);
            u.w = (__float_as_uint(p[2 * kt + 1][2]) >> 16) | ((__float_as_uint(p[2 * kt + 1][3]) >> 16) << 16);
            pf[kt] = as_frag(u);
        }

        // O^T += V^T P^T  (A = vf from permuted vbuf, B = pf)
        __builtin_amdgcn_s_setprio(1);
#pragma unroll
        for (int kt = 0; kt < 2; kt++)
#pragma unroll
            for (int o = 0; o < 8; o++) {
                int vrow = o * 16 + lo;
                s16x8 vf = as_frag(vbuf[vrow * 8 + ((kt * 4 + quad) ^ (vrow & 7))]);
                acc_o[o] = __builtin_amdgcn_mfma_f32_16x16x32_bf16(vf, pf[kt], acc_o[o], 0, 0, 0);
            }
        __builtin_amdgcn_s_setprio(0);
        __syncthreads();
    }

    l_i += __shfl_xor(l_i, 16);
    l_i += __shfl_xor(l_i, 32);

    constexpr int NCH = chunks128(CH);
    size_t pr = (size_t)(batch * NCH + slot) * 128 + wv * 16 + lo;
    float* Op = Opart + pr * 128;
#pragma unroll
    for (int o = 0; o < 8; o++) {
        float4 v = {acc_o[o][0], acc_o[o][1], acc_o[o][2], acc_o[o][3]};
        *(float4*)(Op + o * 16 + quad * 4) = v;
    }
    if (quad == 0) { Mpart[pr] = m_i; Lpart[pr] = l_i; }
}

// ---------------------------------------------------------------------------
// Kernel 4: combine variable-count partials (128-row block layout), online
// flash-rescale. Slot base for qb via closed form F(n) = sum ceil(m/(CH/2)).
// ---------------------------------------------------------------------------
template <int CH>
__global__ __launch_bounds__(256) void k_comb(const float* __restrict__ Opart,
                                              const float* __restrict__ Mpart,
                                              const float* __restrict__ Lpart,
                                              float* __restrict__ out) {
    constexpr int NCH = chunks128(CH);
    constexpr int H2 = CH / 2;
    int tid = threadIdx.x;
    int row = blockIdx.x * 8 + (tid >> 5);
    int h4 = (tid & 31) * 4;
    int batch = row >> 12, t = row & 4095, qb = t >> 7, rr = t & 127;
    int nc = (2 * qb + 1 + CH) / CH;
    int n = qb + 1, k = n / H2, r = n % H2;
    int F = H2 * k * (k + 1) / 2 + r * (k + 1);
    int base = NCH - F;
    float M = -INFINITY, den = 0.f;
    float4 o = {0.f, 0.f, 0.f, 0.f};
    for (int s = 0; s < nc; ++s) {
        size_t pr = (size_t)(batch * NCH + base + s) * 128 + rr;
        float ms = Mpart[pr], ls = Lpart[pr];
        float4 v = *(const float4*)(Opart + pr * 128 + h4);
        float Mn = fmaxf(M, ms);
        float wa = exp2f(M - Mn), wb = exp2f(ms - Mn);
        den = den * wa + ls * wb;
        o.x = o.x * wa + v.x * wb;
        o.y = o.y * wa + v.y * wb;
        o.z = o.z * wa + v.z * wb;
        o.w = o.w * wa + v.w * wb;
        M = Mn;
    }
    float inv = 1.0f / den;
    float4 rz = {o.x * inv, o.y * inv, o.z * inv, o.w * inv};
    *(float4*)(out + (size_t)row * H_ + h4) = rz;
}

// ---------------------------------------------------------------------------
extern "C" void kernel_launch(void* const* d_in, const int* in_sizes, int n_in,
                              void* d_out, int out_size, void* d_ws, size_t ws_size,
                              hipStream_t stream) {
    const float* x  = (const float*)d_in[0];
    const float* Wk = (const float*)d_in[1];
    const float* Wq = (const float*)d_in[2];
    const float* Wv = (const float*)d_in[3];
    char* ws = (char*)d_ws;
    unsigned short* Wt = (unsigned short*)ws;                 // 768 KB
    unsigned short* Qb = (unsigned short*)(ws + (1u << 20));  // 4 MB
    unsigned short* Kb = (unsigned short*)(ws + (5u << 20));  // 4 MB
    unsigned short* Vt = (unsigned short*)(ws + (9u << 20));  // 4 MB -> end 13 MB
    float* out = (float*)d_out;

    const size_t base = (size_t)13 << 20;
    constexpr int N6  = chunks128(6);   // 187 chunks/batch -> 748 blocks, ~3/CU
    constexpr int N10 = chunks128(10);  // 119 chunks/batch -> 476 blocks (fits known ws)
    // per chunk: 128 rows x (128 f32 O + M + L)
    auto need_for = [&](int nch) {
        return base + (size_t)4 * nch * 128 * (128 * 4) + 2 * (size_t)4 * nch * 128 * 4;
    };

    k_wt  <<<dim3(16, 2, 3), 256, 0, stream>>>(Wk, Wq, Wv, Wt);
    k_qkv <<<dim3(256, 2), 256, 0, stream>>>(x, Wt, Qb, Kb, Vt);

    if (ws_size >= need_for(N6)) {
        float* Op = (float*)(ws + base);
        float* Mp = Op + (size_t)4 * N6 * 128 * 128;
        float* Lp = Mp + (size_t)4 * N6 * 128;
        k_attn<6><<<4 * N6, 512, 0, stream>>>(Qb, Kb, Vt, Op, Mp, Lp);
        k_comb<6><<<2048, 256, 0, stream>>>(Op, Mp, Lp, out);
    } else {
        float* Op = (float*)(ws + base);
        float* Mp = Op + (size_t)4 * N10 * 128 * 128;
        float* Lp = Mp + (size_t)4 * N10 * 128;
        k_attn<10><<<4 * N10, 512, 0, stream>>>(Qb, Kb, Vt, Op, Mp, Lp);
        k_comb<10><<<2048, 256, 0, stream>>>(Op, Mp, Lp, out);
    }
}

// Round 7
// 161.329 us; speedup vs baseline: 1.4331x; 1.4331x over previous
//
#include <hip/hip_runtime.h>
#include <stdint.h>
#include <math.h>

#define B_ 4
#define T_ 4096
#define C_ 1024
#define H_ 128

typedef __attribute__((ext_vector_type(8))) short s16x8;   // 8 bf16 (4 VGPRs)
typedef __attribute__((ext_vector_type(4))) float f32x4;   // MFMA accumulator

__device__ __forceinline__ unsigned short f2bf(float f) {
    union { float f; unsigned u; } v; v.f = f;
    unsigned r = v.u + 0x7fffu + ((v.u >> 16) & 1u);
    return (unsigned short)(r >> 16);
}

__device__ __forceinline__ s16x8 as_frag(uint4 u) {
    union { uint4 u; s16x8 s; } v; v.u = u; return v.s;
}

// chunks per batch for 128-query blocks, CH key-tiles per chunk (CH even).
// q-block qb (0..31) has 2qb+2 key-tiles; nc(qb) = ceil((qb+1)/(CH/2)).
__host__ __device__ constexpr int chunks128(int CH) {
    int H2 = CH / 2;
    int k = 32 / H2, r = 32 % H2;
    return H2 * k * (k + 1) / 2 + r * (k + 1);
}

// softmax scale folded into Q at projection time: 1/sqrt(128) * log2(e)
#define QSC (0.0883883476f * 1.4426950408f)

// ---------------------------------------------------------------------------
// Kernel 1: W [1024][128] fp32 -> Wt [3*128][1024] bf16 (transposed, converted)
// ---------------------------------------------------------------------------
__global__ __launch_bounds__(256) void k_wt(const float* __restrict__ Wk,
                                            const float* __restrict__ Wq,
                                            const float* __restrict__ Wv,
                                            unsigned short* __restrict__ Wt) {
    __shared__ float tile[64][65];
    int w = blockIdx.z;  // 0=K, 1=Q, 2=V
    const float* W = (w == 0) ? Wk : (w == 1) ? Wq : Wv;
    int c0 = blockIdx.x * 64, h0 = blockIdx.y * 64;
    int tid = threadIdx.x;
#pragma unroll
    for (int k = 0; k < 16; k++) {
        int idx = tid + k * 256;
        int r = idx >> 6, c = idx & 63;
        tile[r][c] = W[(size_t)(c0 + r) * H_ + h0 + c];
    }
    __syncthreads();
#pragma unroll
    for (int k = 0; k < 16; k++) {
        int idx = tid + k * 256;
        int hh = idx >> 6, cc = idx & 63;
        Wt[(size_t)(w * H_ + h0 + hh) * C_ + c0 + cc] = f2bf(tile[cc][hh]);
    }
}

// ---------------------------------------------------------------------------
// Kernel 2: fused QKV GEMM — ROUND-0 EXACT (best measured: 43.1us, VGPR 64).
// V is written t-PERMUTED within each 32-block (consumed by k_attn PV order).
// ---------------------------------------------------------------------------
__global__ __launch_bounds__(256, 3) void k_qkv(const float* __restrict__ x,
                                                const unsigned short* __restrict__ Wt,
                                                unsigned short* __restrict__ Qb,
                                                unsigned short* __restrict__ Kb,
                                                unsigned short* __restrict__ Vt) {
    __shared__ unsigned short a_lds[2][64 * 72];  // 2 x 9216 B
    int tid = threadIdx.x;
    int wv = tid >> 6, lane = tid & 63, quad = lane >> 4, lo = lane & 15;
    int r0 = blockIdx.x * 64;
    int cb = blockIdx.y;
    int nt0 = wv * 3;

    f32x4 acc[3][4];
#pragma unroll
    for (int i = 0; i < 3; i++)
#pragma unroll
        for (int j = 0; j < 4; j++) acc[i][j] = (f32x4){0.f, 0.f, 0.f, 0.f};

    const int row_s = tid >> 2;
    const int seg_s = (tid & 3) * 16;
    size_t xbase = (size_t)(r0 + row_s) * C_ + seg_s;

    const unsigned short* wp[3];
#pragma unroll
    for (int nt = 0; nt < 3; nt++)
        wp[nt] = Wt + (size_t)(cb * 192 + (nt0 + nt) * 16 + lo) * C_ + quad * 8;

    auto pack_store = [&](unsigned short* buf, const float4 (&f)[4]) {
        uint4 u0, u1;
        u0.x = (unsigned)f2bf(f[0].x) | ((unsigned)f2bf(f[0].y) << 16);
        u0.y = (unsigned)f2bf(f[0].z) | ((unsigned)f2bf(f[0].w) << 16);
        u0.z = (unsigned)f2bf(f[1].x) | ((unsigned)f2bf(f[1].y) << 16);
        u0.w = (unsigned)f2bf(f[1].z) | ((unsigned)f2bf(f[1].w) << 16);
        u1.x = (unsigned)f2bf(f[2].x) | ((unsigned)f2bf(f[2].y) << 16);
        u1.y = (unsigned)f2bf(f[2].z) | ((unsigned)f2bf(f[2].w) << 16);
        u1.z = (unsigned)f2bf(f[3].x) | ((unsigned)f2bf(f[3].y) << 16);
        u1.w = (unsigned)f2bf(f[3].z) | ((unsigned)f2bf(f[3].w) << 16);
        *(uint4*)&buf[row_s * 72 + seg_s] = u0;
        *(uint4*)&buf[row_s * 72 + seg_s + 8] = u1;
    };
    auto load_x = [&](float4 (&f)[4], int kc) {
        const float* xp = x + xbase + kc * 64;
#pragma unroll
        for (int j = 0; j < 4; j++) f[j] = *(const float4*)(xp + j * 4);
    };

    float4 xr[4];
    load_x(xr, 0);
    pack_store(a_lds[0], xr);
    __syncthreads();

    for (int kc = 0; kc < 16; kc++) {
        const unsigned short* buf = a_lds[kc & 1];
        float4 xn[4];
        if (kc < 15) load_x(xn, kc + 1);  // HBM prefetch; lands during gemm
        s16x8 b[3][2];
#pragma unroll
        for (int nt = 0; nt < 3; nt++)
#pragma unroll
            for (int kh = 0; kh < 2; kh++)
                b[nt][kh] = *(const s16x8*)(wp[nt] + kc * 64 + kh * 32);
        s16x8 af[4][2];
#pragma unroll
        for (int mt = 0; mt < 4; mt++)
#pragma unroll
            for (int kh = 0; kh < 2; kh++)
                af[mt][kh] = *(const s16x8*)&buf[(mt * 16 + lo) * 72 + kh * 32 + quad * 8];
#pragma unroll
        for (int nt = 0; nt < 3; nt++)
#pragma unroll
            for (int kh = 0; kh < 2; kh++)
#pragma unroll
                for (int mt = 0; mt < 4; mt++)
                    acc[nt][mt] = __builtin_amdgcn_mfma_f32_16x16x32_bf16(
                        af[mt][kh], b[nt][kh], acc[nt][mt], 0, 0, 0);
        if (kc < 15) pack_store((unsigned short*)a_lds[(kc & 1) ^ 1], xn);
        __syncthreads();  // next buf ready AND current buf's reads done
    }

    // Epilogue. C-layout: row = mt*16 + quad*4 + r, col = cb*192 + (nt0+nt)*16 + lo
#pragma unroll
    for (int nt = 0; nt < 3; nt++) {
        int col = cb * 192 + (nt0 + nt) * 16 + lo;
        int w = col >> 7, h = col & 127;
#pragma unroll
        for (int mt = 0; mt < 4; mt++) {
            int mrow = r0 + mt * 16 + quad * 4;
            if (w == 2) {
                int b = mrow >> 12, t0 = mrow & 4095;
                // permuted t within 32-block (see k_attn PV fragment order)
                int tp = (t0 & ~31) + (((t0 & 15) >> 2) << 3) + (((t0 >> 4) & 1) << 2);
                uint2 pk;
                pk.x = (unsigned)f2bf(acc[nt][mt][0]) | ((unsigned)f2bf(acc[nt][mt][1]) << 16);
                pk.y = (unsigned)f2bf(acc[nt][mt][2]) | ((unsigned)f2bf(acc[nt][mt][3]) << 16);
                *(uint2*)(Vt + (size_t)(b * H_ + h) * T_ + tp) = pk;
            } else if (w == 1) {
                unsigned short* dst = Qb + (size_t)mrow * H_ + h;
#pragma unroll
                for (int r = 0; r < 4; r++)
                    dst[(size_t)r * H_] = f2bf(acc[nt][mt][r] * QSC);
            } else {
                unsigned short* dst = Kb + (size_t)mrow * H_ + h;
#pragma unroll
                for (int r = 0; r < 4; r++)
                    dst[(size_t)r * H_] = f2bf(acc[nt][mt][r]);
            }
        }
    }
}

// ---------------------------------------------------------------------------
// Kernel 3: causal flash attention, 128-QUERY BLOCKS (512 thr, 8 waves).
// ROUND-7 FIX: round 6 declared __launch_bounds__(512,6) -> VGPR cap ~84 ->
// compiler SPILLED acc_o to scratch (VGPR_Count=40, 376MB HBM traffic/dispatch
// = spill writes, 97us). (512,4) caps at 128 (per-thread need ~100): no spill,
// 2 blocks/CU = 16 waves/CU (same as the 43us round-5 config).
// CH=10: 476 blocks <= 512 residency slots -> whole grid co-resident, no tail.
// Mechanism under test (unchanged): 8 waves share ONE K/V staging -> tile-units
// 8320 -> 4224, K/V traffic + staging writes + barriers per unit work halve.
// ---------------------------------------------------------------------------
#define LOAD_KV(kv0)                                                            \
    do {                                                                        \
        const uint4* kg = (const uint4*)(Kb + (size_t)(batch * T_ + (kv0) + srow_k) * H_); \
        pk0 = kg[sseg_k + 0]; pk1 = kg[sseg_k + 1];                             \
        const uint4* vg = (const uint4*)(Vt + (size_t)(batch * H_ + srow_v) * T_ + (kv0)); \
        pv0 = vg[sseg_v + 0]; pv1 = vg[sseg_v + 1];                             \
    } while (0)

template <int CH>
__global__ __launch_bounds__(512, 4) void k_attn(const unsigned short* __restrict__ Qb,
                                                 const unsigned short* __restrict__ Kb,
                                                 const unsigned short* __restrict__ Vt,
                                                 float* __restrict__ Opart,
                                                 float* __restrict__ Mpart,
                                                 float* __restrict__ Lpart) {
    __shared__ uint4 kbuf[64 * 16];   // 16 KB (64 keys x 128d, swizzled)
    __shared__ uint4 vbuf[128 * 8];   // 16 KB (t-permuted V^T rows)

    int tid = threadIdx.x;
    int wv = tid >> 6, lane = tid & 63, quad = lane >> 4, lo = lane & 15;

    int id = blockIdx.x;
    int batch = id & 3;
    int slot = id >> 2;                    // slot ascending <=> qb descending
    int s = slot, q = 31;
    for (;;) { int nc = (2 * q + 1 + CH) / CH; if (s < nc) break; s -= nc; --q; }
    int qb = q;
    int tbeg = s * CH;
    int tend = min(tbeg + CH, 2 * qb + 2);
    int m0 = qb * 128 + wv * 16;
    int query = m0 + lo;

    s16x8 qf[4];
    size_t qrow = (size_t)(batch * T_ + m0 + lo) * H_;
#pragma unroll
    for (int ks = 0; ks < 4; ks++)
        qf[ks] = *(const s16x8*)(Qb + qrow + ks * 32 + quad * 8);

    f32x4 acc_o[8];   // O[query=lo][d = o*16 + quad*4 + r]
#pragma unroll
    for (int o = 0; o < 8; o++) acc_o[o] = (f32x4){0.f, 0.f, 0.f, 0.f};
    float m_i = -INFINITY, l_i = 0.f;   // l_i: per-lane PARTIAL (quad slice)

    // staging map for 512 threads: K 8 thr/row x 32B, V 4 thr/row x 32B
    const int srow_k = tid >> 3, sseg_k = (tid & 7) * 2;
    const int srow_v = tid >> 2, sseg_v = (tid & 3) * 2;

    uint4 pk0, pk1, pv0, pv1;
    LOAD_KV(tbeg * 64);

    for (int t = tbeg; t < tend; ++t) {
        int kv0 = t * 64;
        kbuf[srow_k * 16 + ((sseg_k + 0) ^ (srow_k & 15))] = pk0;
        kbuf[srow_k * 16 + ((sseg_k + 1) ^ (srow_k & 15))] = pk1;
        vbuf[srow_v * 8 + ((sseg_v + 0) ^ (srow_v & 7))] = pv0;
        vbuf[srow_v * 8 + ((sseg_v + 1) ^ (srow_v & 7))] = pv1;
        __syncthreads();
        if (t + 1 < tend) LOAD_KV((t + 1) * 64);

        // S^T = K Q^T: lane holds S[query=lo][key = kv0 + nt*16 + quad*4 + r]
        f32x4 s_acc[4];
#pragma unroll
        for (int nt = 0; nt < 4; nt++) s_acc[nt] = (f32x4){0.f, 0.f, 0.f, 0.f};
        __builtin_amdgcn_s_setprio(1);
#pragma unroll
        for (int ks = 0; ks < 4; ks++) {
#pragma unroll
            for (int nt = 0; nt < 4; nt++) {
                s16x8 kf = as_frag(kbuf[(nt * 16 + lo) * 16 + ((ks * 4 + quad) ^ lo)]);
                s_acc[nt] = __builtin_amdgcn_mfma_f32_16x16x32_bf16(kf, qf[ks], s_acc[nt], 0, 0, 0);
            }
        }
        __builtin_amdgcn_s_setprio(0);

        float p[4][4];
#pragma unroll
        for (int nt = 0; nt < 4; nt++)
#pragma unroll
            for (int r = 0; r < 4; r++) p[nt][r] = s_acc[nt][r];
        if (kv0 + 63 > m0) {  // wave-uniform: tile may contain keys > queries
#pragma unroll
            for (int nt = 0; nt < 4; nt++)
#pragma unroll
                for (int r = 0; r < 4; r++)
                    if (kv0 + nt * 16 + quad * 4 + r > query) p[nt][r] = -INFINITY;
        }

        // per-lane max only; cross-lane work deferred (T13, THR=8)
        float mx = p[0][0];
#pragma unroll
        for (int nt = 0; nt < 4; nt++)
#pragma unroll
            for (int r = 0; r < 4; r++) mx = fmaxf(mx, p[nt][r]);
        if (__any(mx > m_i + 8.0f)) {
            float rm = fmaxf(mx, __shfl_xor(mx, 16));
            rm = fmaxf(rm, __shfl_xor(rm, 32));
            float mnew = fmaxf(m_i, rm);
            float alpha = exp2f(m_i - mnew);
            l_i *= alpha;
            m_i = mnew;
#pragma unroll
            for (int o = 0; o < 8; o++)
#pragma unroll
                for (int r = 0; r < 4; r++) acc_o[o][r] *= alpha;
        }
        float rs = 0.f;
#pragma unroll
        for (int nt = 0; nt < 4; nt++)
#pragma unroll
            for (int r = 0; r < 4; r++) {
                float pv = exp2f(p[nt][r] - m_i);   // bounded by 2^8
                p[nt][r] = pv;
                rs += pv;
            }
        l_i += rs;   // per-lane partial; summed across quads after loop

        // pack P straight into B-fragments (truncation; P in [0, 256])
        s16x8 pf[2];
#pragma unroll
        for (int kt = 0; kt < 2; kt++) {
            uint4 u;
            u.x = (__float_as_uint(p[2 * kt][0]) >> 16) | ((__float_as_uint(p[2 * kt][1]) >> 16) << 16);
            u.y = (__float_as_uint(p[2 * kt][2]) >> 16) | ((__float_as_uint(p[2 * kt][3]) >> 16) << 16);
            u.z = (__float_as_uint(p[2 * kt + 1][0]) >> 16) | ((__float_as_uint(p[2 * kt + 1][1]) >> 16) << 16);
            u.w = (__float_as_uint(p[2 * kt + 1][2]) >> 16) | ((__float_as_uint(p[2 * kt + 1][3]) >> 16) << 16);
            pf[kt] = as_frag(u);
        }

        // O^T += V^T P^T  (A = vf from permuted vbuf, B = pf)
        __builtin_amdgcn_s_setprio(1);
#pragma unroll
        for (int kt = 0; kt < 2; kt++)
#pragma unroll
            for (int o = 0; o < 8; o++) {
                int vrow = o * 16 + lo;
                s16x8 vf = as_frag(vbuf[vrow * 8 + ((kt * 4 + quad) ^ (vrow & 7))]);
                acc_o[o] = __builtin_amdgcn_mfma_f32_16x16x32_bf16(vf, pf[kt], acc_o[o], 0, 0, 0);
            }
        __builtin_amdgcn_s_setprio(0);
        __syncthreads();
    }

    l_i += __shfl_xor(l_i, 16);
    l_i += __shfl_xor(l_i, 32);

    constexpr int NCH = chunks128(CH);
    size_t pr = (size_t)(batch * NCH + slot) * 128 + wv * 16 + lo;
    float* Op = Opart + pr * 128;
#pragma unroll
    for (int o = 0; o < 8; o++) {
        float4 v = {acc_o[o][0], acc_o[o][1], acc_o[o][2], acc_o[o][3]};
        *(float4*)(Op + o * 16 + quad * 4) = v;
    }
    if (quad == 0) { Mpart[pr] = m_i; Lpart[pr] = l_i; }
}

// ---------------------------------------------------------------------------
// Kernel 4: combine variable-count partials (128-row block layout), online
// flash-rescale. Slot base for qb via closed form F(n) = sum ceil(m/(CH/2)).
// ---------------------------------------------------------------------------
template <int CH>
__global__ __launch_bounds__(256) void k_comb(const float* __restrict__ Opart,
                                              const float* __restrict__ Mpart,
                                              const float* __restrict__ Lpart,
                                              float* __restrict__ out) {
    constexpr int NCH = chunks128(CH);
    constexpr int H2 = CH / 2;
    int tid = threadIdx.x;
    int row = blockIdx.x * 8 + (tid >> 5);
    int h4 = (tid & 31) * 4;
    int batch = row >> 12, t = row & 4095, qb = t >> 7, rr = t & 127;
    int nc = (2 * qb + 1 + CH) / CH;
    int n = qb + 1, k = n / H2, r = n % H2;
    int F = H2 * k * (k + 1) / 2 + r * (k + 1);
    int base = NCH - F;
    float M = -INFINITY, den = 0.f;
    float4 o = {0.f, 0.f, 0.f, 0.f};
    for (int s = 0; s < nc; ++s) {
        size_t pr = (size_t)(batch * NCH + base + s) * 128 + rr;
        float ms = Mpart[pr], ls = Lpart[pr];
        float4 v = *(const float4*)(Opart + pr * 128 + h4);
        float Mn = fmaxf(M, ms);
        float wa = exp2f(M - Mn), wb = exp2f(ms - Mn);
        den = den * wa + ls * wb;
        o.x = o.x * wa + v.x * wb;
        o.y = o.y * wa + v.y * wb;
        o.z = o.z * wa + v.z * wb;
        o.w = o.w * wa + v.w * wb;
        M = Mn;
    }
    float inv = 1.0f / den;
    float4 rz = {o.x * inv, o.y * inv, o.z * inv, o.w * inv};
    *(float4*)(out + (size_t)row * H_ + h4) = rz;
}

// ---------------------------------------------------------------------------
extern "C" void kernel_launch(void* const* d_in, const int* in_sizes, int n_in,
                              void* d_out, int out_size, void* d_ws, size_t ws_size,
                              hipStream_t stream) {
    const float* x  = (const float*)d_in[0];
    const float* Wk = (const float*)d_in[1];
    const float* Wq = (const float*)d_in[2];
    const float* Wv = (const float*)d_in[3];
    char* ws = (char*)d_ws;
    unsigned short* Wt = (unsigned short*)ws;                 // 768 KB
    unsigned short* Qb = (unsigned short*)(ws + (1u << 20));  // 4 MB
    unsigned short* Kb = (unsigned short*)(ws + (5u << 20));  // 4 MB
    unsigned short* Vt = (unsigned short*)(ws + (9u << 20));  // 4 MB -> end 13 MB
    float* out = (float*)d_out;

    const size_t base = (size_t)13 << 20;
    constexpr int N10 = chunks128(10);  // 119 chunks/batch -> 476 blocks (all resident @2/CU)
    constexpr int N20 = chunks128(20);  // 68 chunks/batch  -> 272 blocks (smaller ws)
    // per chunk: 128 rows x (128 f32 O + M + L)
    auto need_for = [&](int nch) {
        return base + (size_t)4 * nch * 128 * (128 * 4) + 2 * (size_t)4 * nch * 128 * 4;
    };

    k_wt  <<<dim3(16, 2, 3), 256, 0, stream>>>(Wk, Wq, Wv, Wt);
    k_qkv <<<dim3(256, 2), 256, 0, stream>>>(x, Wt, Qb, Kb, Vt);

    if (ws_size >= need_for(N10)) {
        float* Op = (float*)(ws + base);
        float* Mp = Op + (size_t)4 * N10 * 128 * 128;
        float* Lp = Mp + (size_t)4 * N10 * 128;
        k_attn<10><<<4 * N10, 512, 0, stream>>>(Qb, Kb, Vt, Op, Mp, Lp);
        k_comb<10><<<2048, 256, 0, stream>>>(Op, Mp, Lp, out);
    } else {
        float* Op = (float*)(ws + base);
        float* Mp = Op + (size_t)4 * N20 * 128 * 128;
        float* Lp = Mp + (size_t)4 * N20 * 128;
        k_attn<20><<<4 * N20, 512, 0, stream>>>(Qb, Kb, Vt, Op, Mp, Lp);
        k_comb<20><<<2048, 256, 0, stream>>>(Op, Mp, Lp, out);
    }
}